// Round 5
// baseline (1391.679 us; speedup 1.0000x reference)
//
#include <hip/hip_runtime.h>
#include <cmath>

#define NN 100000     // nodes
#define NE 3200000    // edges
#define CIN 602
#define CH 16
#define COUT 41

// Module-static scratch: independent of ws_size.
__device__ float g_h1[NN * CH];     // x @ W1
__device__ float g_agg1[NN * CH];   // layer-1 scatter accumulator -> relu(mean)+b1
__device__ float g_cnt[NN];         // in-degree counts
__device__ float g_agg2[NN * CH];   // layer-2 scatter accumulator (pre-W2)

__device__ __forceinline__ int clamp_node(int v) {
    return v < 0 ? 0 : (v >= NN ? NN - 1 : v);
}

// ---------------- fallback: if input layout differs, just zero d_out ----------
__global__ __launch_bounds__(256) void fallback_zero_out_k(float* __restrict__ out, int n) {
    int i = blockIdx.x * blockDim.x + threadIdx.x;
    if (i < n) out[i] = 0.0f;
}

// ---------------- zero the accumulators ----------------
__global__ __launch_bounds__(256) void zero_k() {
    int i = blockIdx.x * blockDim.x + threadIdx.x;
    if (i < NN * CH) { g_agg1[i] = 0.f; g_agg2[i] = 0.f; }
    if (i < NN) g_cnt[i] = 0.f;
}

// ---------------- x @ W1 -> g_h1 [NN x CH] ----------------
// One thread per row. W1 accesses are wave-uniform -> scalar loads.
__global__ __launch_bounds__(256) void gemm1_k(const float* __restrict__ x,
                                               const float* __restrict__ W1) {
    int row = blockIdx.x * blockDim.x + threadIdx.x;
    if (row >= NN) return;
    const float* xr = x + (size_t)row * CIN;
    float acc[CH];
#pragma unroll
    for (int c = 0; c < CH; ++c) acc[c] = 0.f;
    // rows are 8-byte aligned (602*4 = 2408 B), CIN even -> float2 covers all
    for (int k = 0; k < CIN; k += 2) {
        float2 xv = *reinterpret_cast<const float2*>(xr + k);
#pragma unroll
        for (int c = 0; c < CH; ++c) {
            acc[c] += xv.x * W1[k * CH + c];
            acc[c] += xv.y * W1[(k + 1) * CH + c];
        }
    }
    float4* hp = reinterpret_cast<float4*>(g_h1 + (size_t)row * CH);  // 64B aligned
#pragma unroll
    for (int v = 0; v < CH / 4; ++v)
        hp[v] = make_float4(acc[4 * v], acc[4 * v + 1], acc[4 * v + 2], acc[4 * v + 3]);
}

// ---------------- layer-1 scatter: g_agg1 += g_h1[src], g_cnt += 1 ------------
// thread = (edge, channel); 16 consecutive threads share an edge.
// Indices clamped: a corrupt ei value gives a wrong (bounded) write, not a fault.
__global__ __launch_bounds__(256) void scatter1_k(const int* __restrict__ ei) {
    unsigned tid = blockIdx.x * blockDim.x + threadIdx.x;
    if (tid >= (unsigned)NE * CH) return;
    unsigned e = tid >> 4;
    unsigned c = tid & 15u;
    int s = clamp_node(ei[e]);
    int d = clamp_node(ei[NE + e]);
    atomicAdd(&g_agg1[(size_t)d * CH + c], g_h1[(size_t)s * CH + c]);
    if (c == 0) atomicAdd(&g_cnt[d], 1.0f);
}

// ---------------- h1 = relu(agg1/max(cnt,1) + b1), in place ----------------
__global__ __launch_bounds__(256) void relu_mean_k(const float* __restrict__ b1) {
    int i = blockIdx.x * blockDim.x + threadIdx.x;
    if (i >= NN * CH) return;
    float cv = fmaxf(g_cnt[i >> 4], 1.0f);
    float v = g_agg1[i] / cv + b1[i & 15];
    g_agg1[i] = fmaxf(v, 0.0f);
}

// ---------------- layer-2 scatter: g_agg2 += g_agg1[src] ----------------
// (aggregate FIRST at 16 ch; W2 applied after -- linearity of segment_sum)
__global__ __launch_bounds__(256) void scatter2_k(const int* __restrict__ ei) {
    unsigned tid = blockIdx.x * blockDim.x + threadIdx.x;
    if (tid >= (unsigned)NE * CH) return;
    unsigned e = tid >> 4;
    unsigned c = tid & 15u;
    int s = clamp_node(ei[e]);
    int d = clamp_node(ei[NE + e]);
    atomicAdd(&g_agg2[(size_t)d * CH + c], g_agg1[(size_t)s * CH + c]);
}

// ---------------- out = log_softmax((agg2/cnt) @ W2 + b2) ----------------
// One wave per node; lanes 0..40 own output channels.
__global__ __launch_bounds__(256) void final_k(const float* __restrict__ W2,
                                               const float* __restrict__ b2,
                                               float* __restrict__ out) {
    int gtid = blockIdx.x * blockDim.x + threadIdx.x;
    int node = gtid >> 6;
    int lane = gtid & 63;
    if (node >= NN) return;
    float inv = 1.0f / fmaxf(g_cnt[node], 1.0f);
    float o = -INFINITY;
    if (lane < COUT) {
        float s = 0.f;
#pragma unroll
        for (int k = 0; k < CH; ++k)   // g_agg2[node*CH+k] is wave-uniform -> scalar
            s += g_agg2[(size_t)node * CH + k] * W2[k * COUT + lane];
        o = s * inv + b2[lane];
    }
    float m = o;
#pragma unroll
    for (int off = 32; off > 0; off >>= 1) m = fmaxf(m, __shfl_xor(m, off, 64));
    float ex = (lane < COUT) ? expf(o - m) : 0.0f;
    float ssum = ex;
#pragma unroll
    for (int off = 32; off > 0; off >>= 1) ssum += __shfl_xor(ssum, off, 64);
    if (lane < COUT) out[(size_t)node * COUT + lane] = o - m - logf(ssum);
}

extern "C" void kernel_launch(void* const* d_in, const int* in_sizes, int n_in,
                              void* d_out, int out_size, void* d_ws, size_t ws_size,
                              hipStream_t stream) {
    (void)d_ws; (void)ws_size;
    float* out = (float*)d_out;

    // Validate the assumed input layout. On ANY mismatch, write zeros to d_out
    // and return: a clean absmax-failure report (signal) instead of a GPU fault
    // (container crash).
    const int expect[6] = {NN * CIN, 2 * NE, CIN * CH, CH, CH * COUT, COUT};
    bool ok = (n_in >= 6) && (out_size == NN * COUT);
    if (ok) {
        for (int i = 0; i < 6; ++i)
            if (in_sizes[i] != expect[i]) { ok = false; break; }
    }
    if (!ok) {
        int n = out_size > 0 ? out_size : 1;
        fallback_zero_out_k<<<(n + 255) / 256, 256, 0, stream>>>(out, n);
        return;
    }

    const float* x  = (const float*)d_in[0];
    const int*   ei = (const int*)d_in[1];
    const float* W1 = (const float*)d_in[2];
    const float* b1 = (const float*)d_in[3];
    const float* W2 = (const float*)d_in[4];
    const float* b2 = (const float*)d_in[5];

    zero_k<<<(NN * CH + 255) / 256, 256, 0, stream>>>();
    gemm1_k<<<(NN + 255) / 256, 256, 0, stream>>>(x, W1);
    scatter1_k<<<(NE * CH + 255) / 256, 256, 0, stream>>>(ei);
    relu_mean_k<<<(NN * CH + 255) / 256, 256, 0, stream>>>(b1);
    scatter2_k<<<(NE * CH + 255) / 256, 256, 0, stream>>>(ei);
    final_k<<<(NN * 64 + 255) / 256, 256, 0, stream>>>(W2, b2, out);
}

// Round 6
// 1324.231 us; speedup vs baseline: 1.0509x; 1.0509x over previous
//
#include <hip/hip_runtime.h>
#include <cmath>

#define NN 100000     // nodes
#define NE 3200000    // edges
#define CIN 602
#define CH 16
#define COUT 41
#define KT 64         // gemm k-tile

// Module-static scratch (independent of ws_size). ~33 MB total.
__device__ float g_h1[NN * CH];     // x @ W1
__device__ float g_h1b[NN * CH];    // relu(mean(agg1)+b1)
__device__ float g_agg2[NN * CH];   // layer-2 aggregation (pre-W2)
__device__ int   g_deg[NN];         // in-degree histogram
__device__ int   g_rs[NN + 1];      // CSR row_start (by dst)
__device__ int   g_cur[NN];         // fill cursors
__device__ int   g_csr[NE];         // src node per edge, grouped by dst

__device__ __forceinline__ int clamp_node(int v) {
    return v < 0 ? 0 : (v >= NN ? NN - 1 : v);
}

// ---------------- fallback: if input layout differs, just zero d_out ----------
__global__ __launch_bounds__(256) void fallback_zero_out_k(float* __restrict__ out, int n) {
    int i = blockIdx.x * blockDim.x + threadIdx.x;
    if (i < n) out[i] = 0.0f;
}

// ---------------- zero degree histogram ----------------
__global__ __launch_bounds__(256) void zero_deg_k() {
    int i = blockIdx.x * blockDim.x + threadIdx.x;
    if (i < NN) g_deg[i] = 0;
}

// ---------------- degree histogram over dst ----------------
__global__ __launch_bounds__(256) void hist_k(const int* __restrict__ ei) {
    int e = blockIdx.x * blockDim.x + threadIdx.x;
    if (e >= NE) return;
    int d = clamp_node(ei[NE + e]);
    atomicAdd(&g_deg[d], 1);
}

// ---------------- exclusive prefix scan of g_deg -> g_rs, g_cur --------------
// Single block, 1024 threads; each owns a contiguous chunk of ~98 elements.
__global__ __launch_bounds__(1024) void scan_k() {
    const int CHUNK = (NN + 1023) / 1024;   // 98
    int t = threadIdx.x;
    int lo = t * CHUNK;
    int hi = lo + CHUNK; if (hi > NN) hi = NN;
    int sum = 0;
    for (int i = lo; i < hi; ++i) sum += g_deg[i];
    __shared__ int sh[1024];
    sh[t] = sum;
    __syncthreads();
    for (int off = 1; off < 1024; off <<= 1) {   // Hillis-Steele inclusive scan
        int v = (t >= off) ? sh[t - off] : 0;
        __syncthreads();
        sh[t] += v;
        __syncthreads();
    }
    int run = sh[t] - sum;                        // exclusive offset
    for (int i = lo; i < hi; ++i) {
        g_rs[i] = run; g_cur[i] = run;
        run += g_deg[i];
    }
    if (t == 1023) g_rs[NN] = sh[1023];           // == NE
}

// ---------------- fill CSR: csr[cur[d]++] = src ----------------
__global__ __launch_bounds__(256) void fill_k(const int* __restrict__ ei) {
    int e = blockIdx.x * blockDim.x + threadIdx.x;
    if (e >= NE) return;
    int s = clamp_node(ei[e]);
    int d = clamp_node(ei[NE + e]);
    int pos = atomicAdd(&g_cur[d], 1);            // in [rs[d], rs[d]+deg[d])
    g_csr[pos] = s;
}

// ---------------- x @ W1 -> g_h1 (LDS-tiled, coalesced) ----------------
// Block handles 64 rows; thread owns 4 rows x 1 col; x fetched exactly once.
__global__ __launch_bounds__(256) void gemm1_k(const float* __restrict__ x,
                                               const float* __restrict__ W1) {
    __shared__ float xs[64][KT + 1];   // +1 pad: conflict-free column reads
    __shared__ float ws[KT][CH];
    int t = threadIdx.x;
    int c  = t & 15;
    int rq = t >> 4;                   // 0..15, owns rows rq*4..rq*4+3
    int row0 = blockIdx.x * 64;
    float acc[4] = {0.f, 0.f, 0.f, 0.f};
    for (int kb = 0; kb < CIN; kb += KT) {
#pragma unroll
        for (int j = 0; j < 16; ++j) {             // stage 64x64 x-tile
            int li = t + 256 * j;
            int rr = li >> 6, kk = li & 63;
            int gk = kb + kk, gr = row0 + rr;
            xs[rr][kk] = (gk < CIN && gr < NN) ? x[(size_t)gr * CIN + gk] : 0.f;
        }
#pragma unroll
        for (int j = 0; j < 4; ++j) {              // stage 64x16 W1-tile
            int li = t + 256 * j;
            int kk = li >> 4, cc = li & 15;
            int gk = kb + kk;
            ws[kk][cc] = (gk < CIN) ? W1[(size_t)gk * CH + cc] : 0.f;
        }
        __syncthreads();
#pragma unroll 8
        for (int kk = 0; kk < KT; ++kk) {
            float w = ws[kk][c];
#pragma unroll
            for (int i = 0; i < 4; ++i)
                acc[i] += xs[rq * 4 + i][kk] * w;
        }
        __syncthreads();
    }
#pragma unroll
    for (int i = 0; i < 4; ++i) {
        int row = row0 + rq * 4 + i;
        if (row < NN) g_h1[(size_t)row * CH + c] = acc[i];
    }
}

// ---------------- layer-1 gather: h1b = relu(mean_{e->n} h1[src] + b1) -------
// thread = (node, channel-quad); 4 lanes per node read contiguous 64 B.
__global__ __launch_bounds__(256) void gather1_k(const float* __restrict__ b1) {
    int tid = blockIdx.x * blockDim.x + threadIdx.x;
    if (tid >= NN * 4) return;
    int node = tid >> 2, q = tid & 3;
    int start = g_rs[node], end = g_rs[node + 1];
    float4 acc = make_float4(0.f, 0.f, 0.f, 0.f);
    int e = start;
    for (; e + 1 < end; e += 2) {
        int s0 = g_csr[e], s1 = g_csr[e + 1];
        float4 a = *reinterpret_cast<const float4*>(&g_h1[(size_t)s0 * CH + (q << 2)]);
        float4 b = *reinterpret_cast<const float4*>(&g_h1[(size_t)s1 * CH + (q << 2)]);
        acc.x += a.x + b.x; acc.y += a.y + b.y;
        acc.z += a.z + b.z; acc.w += a.w + b.w;
    }
    if (e < end) {
        int s0 = g_csr[e];
        float4 a = *reinterpret_cast<const float4*>(&g_h1[(size_t)s0 * CH + (q << 2)]);
        acc.x += a.x; acc.y += a.y; acc.z += a.z; acc.w += a.w;
    }
    float inv = 1.0f / fmaxf((float)(end - start), 1.0f);
    float4 bv = reinterpret_cast<const float4*>(b1)[q];
    float4 r;
    r.x = fmaxf(acc.x * inv + bv.x, 0.f);
    r.y = fmaxf(acc.y * inv + bv.y, 0.f);
    r.z = fmaxf(acc.z * inv + bv.z, 0.f);
    r.w = fmaxf(acc.w * inv + bv.w, 0.f);
    reinterpret_cast<float4*>(g_h1b)[(size_t)node * 4 + q] = r;
}

// ---------------- layer-2 gather: agg2 = sum_{e->n} h1b[src] ----------------
__global__ __launch_bounds__(256) void gather2_k() {
    int tid = blockIdx.x * blockDim.x + threadIdx.x;
    if (tid >= NN * 4) return;
    int node = tid >> 2, q = tid & 3;
    int start = g_rs[node], end = g_rs[node + 1];
    float4 acc = make_float4(0.f, 0.f, 0.f, 0.f);
    int e = start;
    for (; e + 1 < end; e += 2) {
        int s0 = g_csr[e], s1 = g_csr[e + 1];
        float4 a = *reinterpret_cast<const float4*>(&g_h1b[(size_t)s0 * CH + (q << 2)]);
        float4 b = *reinterpret_cast<const float4*>(&g_h1b[(size_t)s1 * CH + (q << 2)]);
        acc.x += a.x + b.x; acc.y += a.y + b.y;
        acc.z += a.z + b.z; acc.w += a.w + b.w;
    }
    if (e < end) {
        int s0 = g_csr[e];
        float4 a = *reinterpret_cast<const float4*>(&g_h1b[(size_t)s0 * CH + (q << 2)]);
        acc.x += a.x; acc.y += a.y; acc.z += a.z; acc.w += a.w;
    }
    reinterpret_cast<float4*>(g_agg2)[(size_t)node * 4 + q] = acc;
}

// ---------------- out = log_softmax((agg2/deg) @ W2 + b2) ----------------
// One wave per node; lanes 0..40 own output channels.
__global__ __launch_bounds__(256) void final_k(const float* __restrict__ W2,
                                               const float* __restrict__ b2,
                                               float* __restrict__ out) {
    int gtid = blockIdx.x * blockDim.x + threadIdx.x;
    int node = gtid >> 6;
    int lane = gtid & 63;
    if (node >= NN) return;
    float inv = 1.0f / fmaxf((float)g_deg[node], 1.0f);
    float o = -INFINITY;
    if (lane < COUT) {
        float s = 0.f;
#pragma unroll
        for (int k = 0; k < CH; ++k)
            s += g_agg2[(size_t)node * CH + k] * W2[k * COUT + lane];
        o = s * inv + b2[lane];
    }
    float m = o;
#pragma unroll
    for (int off = 32; off > 0; off >>= 1) m = fmaxf(m, __shfl_xor(m, off, 64));
    float ex = (lane < COUT) ? expf(o - m) : 0.0f;
    float ssum = ex;
#pragma unroll
    for (int off = 32; off > 0; off >>= 1) ssum += __shfl_xor(ssum, off, 64);
    if (lane < COUT) out[(size_t)node * COUT + lane] = o - m - logf(ssum);
}

extern "C" void kernel_launch(void* const* d_in, const int* in_sizes, int n_in,
                              void* d_out, int out_size, void* d_ws, size_t ws_size,
                              hipStream_t stream) {
    (void)d_ws; (void)ws_size;
    float* out = (float*)d_out;

    // Validate assumed input layout; on mismatch report cleanly instead of faulting.
    const int expect[6] = {NN * CIN, 2 * NE, CIN * CH, CH, CH * COUT, COUT};
    bool ok = (n_in >= 6) && (out_size == NN * COUT);
    if (ok) {
        for (int i = 0; i < 6; ++i)
            if (in_sizes[i] != expect[i]) { ok = false; break; }
    }
    if (!ok) {
        int n = out_size > 0 ? out_size : 1;
        fallback_zero_out_k<<<(n + 255) / 256, 256, 0, stream>>>(out, n);
        return;
    }

    const float* x  = (const float*)d_in[0];
    const int*   ei = (const int*)d_in[1];
    const float* W1 = (const float*)d_in[2];
    const float* b1 = (const float*)d_in[3];
    const float* W2 = (const float*)d_in[4];
    const float* b2 = (const float*)d_in[5];

    zero_deg_k<<<(NN + 255) / 256, 256, 0, stream>>>();
    hist_k<<<(NE + 255) / 256, 256, 0, stream>>>(ei);
    scan_k<<<1, 1024, 0, stream>>>();
    fill_k<<<(NE + 255) / 256, 256, 0, stream>>>(ei);
    gemm1_k<<<(NN + 63) / 64, 256, 0, stream>>>(x, W1);
    gather1_k<<<(NN * 4 + 255) / 256, 256, 0, stream>>>(b1);
    gather2_k<<<(NN * 4 + 255) / 256, 256, 0, stream>>>();
    final_k<<<(NN * 64 + 255) / 256, 256, 0, stream>>>(W2, b2, out);
}

// Round 7
// 1174.773 us; speedup vs baseline: 1.1846x; 1.1272x over previous
//
#include <hip/hip_runtime.h>
#include <cmath>

#define NN 100000     // nodes
#define NE 3200000    // edges
#define CIN 602
#define CH 16
#define COUT 41
#define TB 128        // gemm rows per block (= threads per block)
#define KTL 32        // gemm k-tile

// Module-static scratch (independent of ws_size). ~33 MB total.
__device__ float g_h1[NN * CH];     // x @ W1
__device__ float g_h1b[NN * CH];    // relu(mean(agg1)+b1)
__device__ float g_agg2[NN * CH];   // layer-2 aggregation (pre-W2)
__device__ int   g_deg[NN];         // in-degree histogram
__device__ int   g_rs[NN + 1];      // CSR row_start (by dst)
__device__ int   g_cur[NN];         // fill cursors
__device__ int   g_csr[NE];         // src node per edge, grouped by dst

__device__ __forceinline__ int clamp_node(int v) {
    return v < 0 ? 0 : (v >= NN ? NN - 1 : v);
}

// ---------------- fallback: if input layout differs, just zero d_out ----------
__global__ __launch_bounds__(256) void fallback_zero_out_k(float* __restrict__ out, int n) {
    int i = blockIdx.x * blockDim.x + threadIdx.x;
    if (i < n) out[i] = 0.0f;
}

// ---------------- zero degree histogram ----------------
__global__ __launch_bounds__(256) void zero_deg_k() {
    int i = blockIdx.x * blockDim.x + threadIdx.x;
    if (i < NN) g_deg[i] = 0;
}

// ---------------- degree histogram over dst ----------------
__global__ __launch_bounds__(256) void hist_k(const int* __restrict__ ei) {
    int e = blockIdx.x * blockDim.x + threadIdx.x;
    if (e >= NE) return;
    int d = clamp_node(ei[NE + e]);
    atomicAdd(&g_deg[d], 1);
}

// ---------------- exclusive prefix scan of g_deg -> g_rs, g_cur --------------
// Single block, 1024 threads; each owns a contiguous chunk of ~98 elements.
__global__ __launch_bounds__(1024) void scan_k() {
    const int CHUNK = (NN + 1023) / 1024;   // 98
    int t = threadIdx.x;
    int lo = t * CHUNK;
    int hi = lo + CHUNK; if (hi > NN) hi = NN;
    int sum = 0;
    for (int i = lo; i < hi; ++i) sum += g_deg[i];
    __shared__ int sh[1024];
    sh[t] = sum;
    __syncthreads();
    for (int off = 1; off < 1024; off <<= 1) {   // Hillis-Steele inclusive scan
        int v = (t >= off) ? sh[t - off] : 0;
        __syncthreads();
        sh[t] += v;
        __syncthreads();
    }
    int run = sh[t] - sum;                        // exclusive offset
    for (int i = lo; i < hi; ++i) {
        g_rs[i] = run; g_cur[i] = run;
        run += g_deg[i];
    }
    if (t == 1023) g_rs[NN] = sh[1023];           // == NE
}

// ---------------- fill CSR: csr[cur[d]++] = src ----------------
__global__ __launch_bounds__(256) void fill_k(const int* __restrict__ ei) {
    int e = blockIdx.x * blockDim.x + threadIdx.x;
    if (e >= NE) return;
    int s = clamp_node(ei[e]);
    int d = clamp_node(ei[NE + e]);
    int pos = atomicAdd(&g_cur[d], 1);            // in [rs[d], rs[d]+deg[d])
    g_csr[pos] = s;
}

// ---------------- x @ W1 -> g_h1 ----------------
// 1 row per thread, 16 channel accs in VGPRs. x staged to LDS transposed via
// float2 (rows only 8B-aligned: 2408 % 16 == 8, float4 would fault on odd
// rows). Inner loop per kk: 1 ds_read_b32 + 16 FMA; W1 address is
// block-uniform -> s_load via scalar cache. Register-prefetch double buffer
// keeps the next tile's global loads in flight during compute.
__global__ __launch_bounds__(TB) void gemm1_k(const float* __restrict__ x,
                                              const float* __restrict__ W1) {
    __shared__ float xs[KTL][TB + 1];  // stride 129: staging stores & reads <=2-way
    const int t = threadIdx.x;
    const int l  = t & 15;             // staging lane within row: kk pair {2l,2l+1}
    const int rg = t >> 4;             // staging row group: rows rg, rg+8, ...
    const int row0 = blockIdx.x * TB;
    const int row  = row0 + t;         // compute row owned by this thread

    float acc[CH];
#pragma unroll
    for (int c = 0; c < CH; ++c) acc[c] = 0.f;

    float2 ld[16];

    // issue the 16 float2 loads for tile at k-offset kb
    auto stage_load = [&](int kb) {
#pragma unroll
        for (int p = 0; p < 16; ++p) {
            int rgl = row0 + rg + 8 * p;
            ld[p] = (rgl < NN)
                ? *reinterpret_cast<const float2*>(x + (size_t)rgl * CIN + kb + 2 * l)
                : make_float2(0.f, 0.f);
        }
    };
    // epilogue tile (kb=576): only kk<26 valid
    auto stage_load_ep = [&]() {
#pragma unroll
        for (int p = 0; p < 16; ++p) {
            int rgl = row0 + rg + 8 * p;
            ld[p] = (rgl < NN && l <= 12)
                ? *reinterpret_cast<const float2*>(x + (size_t)rgl * CIN + 576 + 2 * l)
                : make_float2(0.f, 0.f);
        }
    };
    auto stage_store = [&]() {
#pragma unroll
        for (int p = 0; p < 16; ++p) {
            int rl = rg + 8 * p;
            xs[2 * l][rl]     = ld[p].x;
            xs[2 * l + 1][rl] = ld[p].y;
        }
    };

    stage_load(0);
    for (int ti = 0; ti < 18; ++ti) {
        stage_store();
        __syncthreads();
        if (ti < 17) stage_load(KTL * (ti + 1)); else stage_load_ep();
        const int kb = KTL * ti;
#pragma unroll 8
        for (int kk = 0; kk < KTL; ++kk) {
            float xv = xs[kk][t];
            const float4* w4 = reinterpret_cast<const float4*>(W1 + (size_t)(kb + kk) * CH);
            float4 w0 = w4[0], w1 = w4[1], w2 = w4[2], w3 = w4[3];
            acc[0]  += xv * w0.x; acc[1]  += xv * w0.y; acc[2]  += xv * w0.z; acc[3]  += xv * w0.w;
            acc[4]  += xv * w1.x; acc[5]  += xv * w1.y; acc[6]  += xv * w1.z; acc[7]  += xv * w1.w;
            acc[8]  += xv * w2.x; acc[9]  += xv * w2.y; acc[10] += xv * w2.z; acc[11] += xv * w2.w;
            acc[12] += xv * w3.x; acc[13] += xv * w3.y; acc[14] += xv * w3.z; acc[15] += xv * w3.w;
        }
        __syncthreads();
    }
    // epilogue tile: kk in [0,26)
    stage_store();
    __syncthreads();
#pragma unroll 13
    for (int kk = 0; kk < 26; ++kk) {
        float xv = xs[kk][t];
        const float4* w4 = reinterpret_cast<const float4*>(W1 + (size_t)(576 + kk) * CH);
        float4 w0 = w4[0], w1 = w4[1], w2 = w4[2], w3 = w4[3];
        acc[0]  += xv * w0.x; acc[1]  += xv * w0.y; acc[2]  += xv * w0.z; acc[3]  += xv * w0.w;
        acc[4]  += xv * w1.x; acc[5]  += xv * w1.y; acc[6]  += xv * w1.z; acc[7]  += xv * w1.w;
        acc[8]  += xv * w2.x; acc[9]  += xv * w2.y; acc[10] += xv * w2.z; acc[11] += xv * w2.w;
        acc[12] += xv * w3.x; acc[13] += xv * w3.y; acc[14] += xv * w3.z; acc[15] += xv * w3.w;
    }

    if (row < NN) {
        float4* hp = reinterpret_cast<float4*>(g_h1 + (size_t)row * CH);
        hp[0] = make_float4(acc[0],  acc[1],  acc[2],  acc[3]);
        hp[1] = make_float4(acc[4],  acc[5],  acc[6],  acc[7]);
        hp[2] = make_float4(acc[8],  acc[9],  acc[10], acc[11]);
        hp[3] = make_float4(acc[12], acc[13], acc[14], acc[15]);
    }
}

// ---------------- layer-1 gather: h1b = relu(mean_{e->n} h1[src] + b1) -------
// thread = (node, channel-quad); 4 lanes per node read contiguous 64 B.
__global__ __launch_bounds__(256) void gather1_k(const float* __restrict__ b1) {
    int tid = blockIdx.x * blockDim.x + threadIdx.x;
    if (tid >= NN * 4) return;
    int node = tid >> 2, q = tid & 3;
    int start = g_rs[node], end = g_rs[node + 1];
    float4 acc = make_float4(0.f, 0.f, 0.f, 0.f);
    int e = start;
    for (; e + 1 < end; e += 2) {
        int s0 = g_csr[e], s1 = g_csr[e + 1];
        float4 a = *reinterpret_cast<const float4*>(&g_h1[(size_t)s0 * CH + (q << 2)]);
        float4 b = *reinterpret_cast<const float4*>(&g_h1[(size_t)s1 * CH + (q << 2)]);
        acc.x += a.x + b.x; acc.y += a.y + b.y;
        acc.z += a.z + b.z; acc.w += a.w + b.w;
    }
    if (e < end) {
        int s0 = g_csr[e];
        float4 a = *reinterpret_cast<const float4*>(&g_h1[(size_t)s0 * CH + (q << 2)]);
        acc.x += a.x; acc.y += a.y; acc.z += a.z; acc.w += a.w;
    }
    float inv = 1.0f / fmaxf((float)(end - start), 1.0f);
    float4 bv = reinterpret_cast<const float4*>(b1)[q];
    float4 r;
    r.x = fmaxf(acc.x * inv + bv.x, 0.f);
    r.y = fmaxf(acc.y * inv + bv.y, 0.f);
    r.z = fmaxf(acc.z * inv + bv.z, 0.f);
    r.w = fmaxf(acc.w * inv + bv.w, 0.f);
    reinterpret_cast<float4*>(g_h1b)[(size_t)node * 4 + q] = r;
}

// ---------------- layer-2 gather: agg2 = sum_{e->n} h1b[src] ----------------
__global__ __launch_bounds__(256) void gather2_k() {
    int tid = blockIdx.x * blockDim.x + threadIdx.x;
    if (tid >= NN * 4) return;
    int node = tid >> 2, q = tid & 3;
    int start = g_rs[node], end = g_rs[node + 1];
    float4 acc = make_float4(0.f, 0.f, 0.f, 0.f);
    int e = start;
    for (; e + 1 < end; e += 2) {
        int s0 = g_csr[e], s1 = g_csr[e + 1];
        float4 a = *reinterpret_cast<const float4*>(&g_h1b[(size_t)s0 * CH + (q << 2)]);
        float4 b = *reinterpret_cast<const float4*>(&g_h1b[(size_t)s1 * CH + (q << 2)]);
        acc.x += a.x + b.x; acc.y += a.y + b.y;
        acc.z += a.z + b.z; acc.w += a.w + b.w;
    }
    if (e < end) {
        int s0 = g_csr[e];
        float4 a = *reinterpret_cast<const float4*>(&g_h1b[(size_t)s0 * CH + (q << 2)]);
        acc.x += a.x; acc.y += a.y; acc.z += a.z; acc.w += a.w;
    }
    reinterpret_cast<float4*>(g_agg2)[(size_t)node * 4 + q] = acc;
}

// ---------------- out = log_softmax((agg2/deg) @ W2 + b2) ----------------
// One wave per node; lanes 0..40 own output channels.
__global__ __launch_bounds__(256) void final_k(const float* __restrict__ W2,
                                               const float* __restrict__ b2,
                                               float* __restrict__ out) {
    int gtid = blockIdx.x * blockDim.x + threadIdx.x;
    int node = gtid >> 6;
    int lane = gtid & 63;
    if (node >= NN) return;
    float inv = 1.0f / fmaxf((float)g_deg[node], 1.0f);
    float o = -INFINITY;
    if (lane < COUT) {
        float s = 0.f;
#pragma unroll
        for (int k = 0; k < CH; ++k)
            s += g_agg2[(size_t)node * CH + k] * W2[k * COUT + lane];
        o = s * inv + b2[lane];
    }
    float m = o;
#pragma unroll
    for (int off = 32; off > 0; off >>= 1) m = fmaxf(m, __shfl_xor(m, off, 64));
    float ex = (lane < COUT) ? expf(o - m) : 0.0f;
    float ssum = ex;
#pragma unroll
    for (int off = 32; off > 0; off >>= 1) ssum += __shfl_xor(ssum, off, 64);
    if (lane < COUT) out[(size_t)node * COUT + lane] = o - m - logf(ssum);
}

extern "C" void kernel_launch(void* const* d_in, const int* in_sizes, int n_in,
                              void* d_out, int out_size, void* d_ws, size_t ws_size,
                              hipStream_t stream) {
    (void)d_ws; (void)ws_size;
    float* out = (float*)d_out;

    // Validate assumed input layout; on mismatch report cleanly instead of faulting.
    const int expect[6] = {NN * CIN, 2 * NE, CIN * CH, CH, CH * COUT, COUT};
    bool ok = (n_in >= 6) && (out_size == NN * COUT);
    if (ok) {
        for (int i = 0; i < 6; ++i)
            if (in_sizes[i] != expect[i]) { ok = false; break; }
    }
    if (!ok) {
        int n = out_size > 0 ? out_size : 1;
        fallback_zero_out_k<<<(n + 255) / 256, 256, 0, stream>>>(out, n);
        return;
    }

    const float* x  = (const float*)d_in[0];
    const int*   ei = (const int*)d_in[1];
    const float* W1 = (const float*)d_in[2];
    const float* b1 = (const float*)d_in[3];
    const float* W2 = (const float*)d_in[4];
    const float* b2 = (const float*)d_in[5];

    zero_deg_k<<<(NN + 255) / 256, 256, 0, stream>>>();
    hist_k<<<(NE + 255) / 256, 256, 0, stream>>>(ei);
    scan_k<<<1, 1024, 0, stream>>>();
    fill_k<<<(NE + 255) / 256, 256, 0, stream>>>(ei);
    gemm1_k<<<(NN + TB - 1) / TB, TB, 0, stream>>>(x, W1);
    gather1_k<<<(NN * 4 + 255) / 256, 256, 0, stream>>>(b1);
    gather2_k<<<(NN * 4 + 255) / 256, 256, 0, stream>>>();
    final_k<<<(NN * 64 + 255) / 256, 256, 0, stream>>>(W2, b2, out);
}